// Round 9
// baseline (2673.556 us; speedup 1.0000x reference)
//
#include <hip/hip_runtime.h>

// ---------------------------------------------------------------------------
// MPNEncoder (chemprop D-MPNN) forward. MI355X/gfx950.
//   A=100000 atoms, B=200000 bonds, NB=6, H=256, FA=133, FB=147, M=5000, DEPTH=4
//
// Established facts:
//   - inputs fp32, output fp32; ws_size >= 358,432,768 B safe (do not exceed)
//   - sizes[-1] negative: pool uses jnp.repeat drop semantics
//   - split-bf16 MFMA (hi*hi+hi*lo+lo*hi) numerically free (absmax 1.72e10
//     unchanged rounds 7-8, thr 4.84e10)
//   - round 8: 2252 us. Bond kernel 324 us x3: MfmaUtil 16%, VALU 22%,
//     HBM 21%, occ 21% (2 waves/SIMD, ~172 unified regs) -> latency/barrier
//     bound. This round: pipelined double-buffer bond K-loop (1 barrier/iter,
//     staging preload overlaps MFMA) + vectorized agg (4 atoms/block, f16x4).
//
// ws layout (total 358,432,768 B):
//   [offsets 32 KB][matom fp32 A*256][mb0 B*256 f16][mb1 B*256 f16]
//   [wsplit tail 51.2 MB: persistent pre-split W (2.1 MB used)]
//   end-phase: aggbuf fp32 = mb0; iatom bf16 = mb1[0:51.2MB];
//              t1 bf16 = mb1[51.2:102.4MB]; hid fp32 = mb0 (after cat)
// ---------------------------------------------------------------------------

typedef _Float16 f16;
typedef f16 f16x4 __attribute__((ext_vector_type(4)));
typedef __attribute__((ext_vector_type(8))) short bh8;    // 8 bf16 (4 VGPR)
typedef __attribute__((ext_vector_type(4))) float f32x4;  // MFMA C/D

#define MB_SCALE 0.000244140625f  /* 2^-12 */
#define MB_INV   4096.0f          /* 2^12  */
#define AGG_INV  16777216.0f      /* 2^24  */

__device__ __forceinline__ unsigned short f2bf_rne(float f) {
    unsigned u = __float_as_uint(f);
    unsigned r = (u + 0x7fffu + ((u >> 16) & 1u)) >> 16;
    return (unsigned short)r;
}
__device__ __forceinline__ float bfu2f(unsigned short u) {
    return __uint_as_float(((unsigned)u) << 16);
}
__device__ __forceinline__ f32x4 mfma16(bh8 a, bh8 b, f32x4 c) {
    return __builtin_amdgcn_mfma_f32_16x16x32_bf16(a, b, c, 0, 0, 0);
}

// ---------------------------------------------------------------------------
// Pre-split all weights once: transposed [n][k] (k contiguous), bf16 hi/lo.
// ---------------------------------------------------------------------------
__global__ __launch_bounds__(256) void wprep_kernel(
    const float* __restrict__ Wia, const float* __restrict__ Wib,
    const float* __restrict__ Wh,  const float* __restrict__ Wlr,
    const float* __restrict__ Wo,  short* __restrict__ ws)
{
    short* WiaT_hi = ws;
    short* WiaT_lo = ws + 40960;
    short* WibT_hi = ws + 81920;
    short* WibT_lo = ws + 122880;
    short* WhT_hi  = ws + 163840;
    short* WhT_lo  = ws + 360448;
    short* WlrT_hi = ws + 557056;
    short* WlrT_lo = ws + 753664;
    short* WoT_hi  = ws + 950272;
    short* WoT_lo  = ws + 1015808;

    int idx = blockIdx.x * 256 + threadIdx.x;
    float v; short *ph, *pl; int o;
    if (idx < 40960) {
        int n = idx / 160, k = idx - n * 160;
        v = (k < 133) ? Wia[(size_t)k * 256 + n] : 0.f;
        ph = WiaT_hi; pl = WiaT_lo; o = idx;
    } else if (idx < 81920) {
        int j = idx - 40960;
        int n = j / 160, k = j - n * 160;
        v = (k < 147) ? Wib[(size_t)k * 256 + n] : 0.f;
        ph = WibT_hi; pl = WibT_lo; o = j;
    } else if (idx < 278528) {
        int j = idx - 81920;
        int d = j >> 16, rem = j & 65535, n = rem >> 8, k = rem & 255;
        v = Wh[(size_t)d * 65536 + (size_t)k * 256 + n];
        ph = WhT_hi; pl = WhT_lo; o = j;
    } else if (idx < 475136) {
        int j = idx - 278528;
        int n = j / 768, k = j - n * 768;
        v = Wlr[(size_t)k * 256 + n];
        ph = WlrT_hi; pl = WlrT_lo; o = j;
    } else if (idx < 540672) {
        int j = idx - 475136;
        int n = j >> 8, k = j & 255;
        v = Wo[(size_t)k * 256 + n];
        ph = WoT_hi; pl = WoT_lo; o = j;
    } else return;
    unsigned short hb = f2bf_rne(v);
    ph[o] = (short)hb;
    pl[o] = (short)f2bf_rne(v - bfu2f(hb));
}

// ---------------------------------------------------------------------------
// Unified split-bf16 MFMA GEMM (round-8 kernel, unchanged).
// SRC 0: A = fp32 X [M,Kact] (zero-pad to KPAD)
// SRC 1: A = [aggb f32 | matom f32 | iatom bf16], K=768
// SRC 2: A = bf16 X [M,256] (no lo term)
// EPI 0: relu->f32  1: relu->bf16  2: relu*MB_SCALE->f16  3: raw->bf16
// EPI 4: relu(x+bias)->f32
// ---------------------------------------------------------------------------
template <int KPAD, int SRC, int EPI>
__global__ __launch_bounds__(256) void mfma_gemm(
    const void* __restrict__ a0, const void* __restrict__ a1,
    const void* __restrict__ a2,
    const short* __restrict__ Bhi, const short* __restrict__ Blo,
    const float* __restrict__ bias, void* __restrict__ outv,
    int M, int Kact)
{
    __shared__ short As_hi[128 * 40];
    __shared__ short As_lo[(SRC == 2) ? 8 : 128 * 40];

    const int tid  = threadIdx.x;
    const int lane = tid & 63;
    const int w    = tid >> 6;
    const int wm   = (w >> 1) * 64;
    const int wn   = (w & 1) * 64;
    const int row0 = blockIdx.x * 128;
    const int colb = blockIdx.y * 128;

    const int sm = tid >> 1;
    const int sk = (tid & 1) * 16;
    const int fm = lane & 15;
    const int fk = (lane >> 4) * 8;

    int grow = row0 + sm; if (grow > M - 1) grow = M - 1;

    f32x4 acc[4][4];
#pragma unroll
    for (int i = 0; i < 4; ++i)
#pragma unroll
        for (int j = 0; j < 4; ++j) {
            f32x4 z = {0.f, 0.f, 0.f, 0.f};
            acc[i][j] = z;
        }

    for (int k0 = 0; k0 < KPAD; k0 += 32) {
        __syncthreads();
        if (SRC == 0) {
            const float* xrow = (const float*)a0 + (size_t)grow * Kact;
            bh8 h0, h1, l0, l1;
#pragma unroll
            for (int j = 0; j < 8; ++j) {
                int kc = k0 + sk + j;
                float v = (kc < Kact) ? xrow[kc] : 0.f;
                unsigned short hb = f2bf_rne(v);
                h0[j] = (short)hb; l0[j] = (short)f2bf_rne(v - bfu2f(hb));
                int kc2 = kc + 8;
                float v2 = (kc2 < Kact) ? xrow[kc2] : 0.f;
                unsigned short hb2 = f2bf_rne(v2);
                h1[j] = (short)hb2; l1[j] = (short)f2bf_rne(v2 - bfu2f(hb2));
            }
            int base = sm * 40 + sk;
            *(bh8*)&As_hi[base] = h0; *(bh8*)&As_hi[base + 8] = h1;
            *(bh8*)&As_lo[base] = l0; *(bh8*)&As_lo[base + 8] = l1;
        } else if (SRC == 1) {
            int base = sm * 40 + sk;
            if (k0 < 512) {
                const float* src = (k0 < 256) ? (const float*)a0 : (const float*)a1;
                int kl = k0 & 255;
                const float4* p = (const float4*)(src + (size_t)grow * 256 + kl + sk);
                float va[16];
#pragma unroll
                for (int q = 0; q < 4; ++q) {
                    float4 f = p[q];
                    va[q * 4 + 0] = f.x; va[q * 4 + 1] = f.y;
                    va[q * 4 + 2] = f.z; va[q * 4 + 3] = f.w;
                }
                bh8 h0, h1, l0, l1;
#pragma unroll
                for (int j = 0; j < 8; ++j) {
                    unsigned short hb = f2bf_rne(va[j]);
                    h0[j] = (short)hb; l0[j] = (short)f2bf_rne(va[j] - bfu2f(hb));
                    unsigned short hb2 = f2bf_rne(va[8 + j]);
                    h1[j] = (short)hb2; l1[j] = (short)f2bf_rne(va[8 + j] - bfu2f(hb2));
                }
                *(bh8*)&As_hi[base] = h0; *(bh8*)&As_hi[base + 8] = h1;
                *(bh8*)&As_lo[base] = l0; *(bh8*)&As_lo[base + 8] = l1;
            } else {
                const short* ia = (const short*)a2 + (size_t)grow * 256 + (k0 - 512) + sk;
                bh8 z;
#pragma unroll
                for (int j = 0; j < 8; ++j) z[j] = 0;
                *(bh8*)&As_hi[base]     = *(const bh8*)ia;
                *(bh8*)&As_hi[base + 8] = *(const bh8*)(ia + 8);
                *(bh8*)&As_lo[base] = z; *(bh8*)&As_lo[base + 8] = z;
            }
        } else {
            const short* xr = (const short*)a0 + (size_t)grow * 256 + k0 + sk;
            int base = sm * 40 + sk;
            *(bh8*)&As_hi[base]     = *(const bh8*)xr;
            *(bh8*)&As_hi[base + 8] = *(const bh8*)(xr + 8);
        }
        __syncthreads();

        bh8 bhf[4], blf[4];
#pragma unroll
        for (int nt = 0; nt < 4; ++nt) {
            int n = colb + wn + nt * 16 + fm;
            size_t off = (size_t)n * KPAD + k0 + fk;
            bhf[nt] = *(const bh8*)(Bhi + off);
            blf[nt] = *(const bh8*)(Blo + off);
        }
#pragma unroll
        for (int mt = 0; mt < 4; ++mt) {
            int abase = (wm + mt * 16 + fm) * 40 + fk;
            bh8 ah = *(const bh8*)&As_hi[abase];
#pragma unroll
            for (int nt = 0; nt < 4; ++nt) {
                acc[mt][nt] = mfma16(ah, bhf[nt], acc[mt][nt]);
                acc[mt][nt] = mfma16(ah, blf[nt], acc[mt][nt]);
            }
            if (SRC != 2) {
                bh8 al = *(const bh8*)&As_lo[abase];
#pragma unroll
                for (int nt = 0; nt < 4; ++nt)
                    acc[mt][nt] = mfma16(al, bhf[nt], acc[mt][nt]);
            }
        }
    }

#pragma unroll
    for (int mt = 0; mt < 4; ++mt) {
        int rbase = row0 + wm + mt * 16 + (lane >> 4) * 4;
#pragma unroll
        for (int nt = 0; nt < 4; ++nt) {
            int col = colb + wn + nt * 16 + fm;
            float bc = (EPI == 4) ? bias[col] : 0.f;
#pragma unroll
            for (int r = 0; r < 4; ++r) {
                int row = rbase + r;
                if (row < M) {
                    size_t o = (size_t)row * 256 + col;
                    float v = acc[mt][nt][r];
                    if (EPI == 0)      ((float*)outv)[o] = fmaxf(v, 0.f);
                    else if (EPI == 1) ((unsigned short*)outv)[o] = f2bf_rne(fmaxf(v, 0.f));
                    else if (EPI == 2) ((f16*)outv)[o] = (f16)(fmaxf(v, 0.f) * MB_SCALE);
                    else if (EPI == 3) ((unsigned short*)outv)[o] = f2bf_rne(v);
                    else               ((float*)outv)[o] = fmaxf(v + bc, 0.f);
                }
            }
        }
    }
}

// ---------------------------------------------------------------------------
// Bond update, pipelined double-buffer split-bf16 MFMA:
//   mb_new = relu( relu(FB@Wib) + (matom[b2a] - MB_INV*mb_old[b2revb]) @ Wh ) * MB_SCALE
// 13 unified k-iters: 0..4 phase1 (K=160 from FB/Wib), 5..12 phase2 (K=256).
// One barrier per iter; iter i+1's global staging loads issue before iter i's
// MFMA so their latency hides under compute.
// ---------------------------------------------------------------------------
__global__ __launch_bounds__(256) void bond_mfma_kernel(
    const float* __restrict__ FB,
    const short* __restrict__ WibT_hi, const short* __restrict__ WibT_lo,
    const short* __restrict__ WhT_hi,  const short* __restrict__ WhT_lo,
    const float* __restrict__ matom, const f16* __restrict__ mb_old,
    const int* __restrict__ b2a, const int* __restrict__ b2revb,
    f16* __restrict__ mb_new, int M)
{
    __shared__ short As_hi[2][128 * 40];
    __shared__ short As_lo[2][128 * 40];

    const int tid  = threadIdx.x;
    const int lane = tid & 63;
    const int w    = tid >> 6;
    const int wm   = (w >> 1) * 64;
    const int wn   = (w & 1) * 64;
    const int row0 = blockIdx.x * 128;
    const int colb = blockIdx.y * 128;

    const int sm = tid >> 1;
    const int sk = (tid & 1) * 16;
    const int fm = lane & 15;
    const int fk = (lane >> 4) * 8;

    int grow = row0 + sm; if (grow > M - 1) grow = M - 1;
    const float* frow = FB + (size_t)grow * 147;
    const float* arow = matom + (size_t)b2a[grow] * 256;
    const f16*   rrow = mb_old + (size_t)b2revb[grow] * 256;

    f32x4 acc[4][4];
#pragma unroll
    for (int i = 0; i < 4; ++i)
#pragma unroll
        for (int j = 0; j < 4; ++j) {
            f32x4 z = {0.f, 0.f, 0.f, 0.f};
            acc[i][j] = z;
        }

    // staging-value loader: iter 0..4 -> FB (K=160 pad), 5..12 -> fused gather
    auto load_src = [&](int it, float va[16]) {
        if (it < 5) {
            int k0 = it * 32;
#pragma unroll
            for (int j = 0; j < 16; ++j) {
                int kc = k0 + sk + j;
                va[j] = (kc < 147) ? frow[kc] : 0.f;
            }
        } else {
            int k0 = (it - 5) * 32;
            const float4* ap = (const float4*)(arow + k0 + sk);
            const f16x4*  rp = (const f16x4*)(rrow + k0 + sk);
#pragma unroll
            for (int q = 0; q < 4; ++q) {
                float4 a = ap[q]; f16x4 r = rp[q];
                va[q * 4 + 0] = fmaf(-MB_INV, (float)r[0], a.x);
                va[q * 4 + 1] = fmaf(-MB_INV, (float)r[1], a.y);
                va[q * 4 + 2] = fmaf(-MB_INV, (float)r[2], a.z);
                va[q * 4 + 3] = fmaf(-MB_INV, (float)r[3], a.w);
            }
        }
    };
    auto write_lds = [&](int buf, const float va[16]) {
        bh8 h0, h1, l0, l1;
#pragma unroll
        for (int j = 0; j < 8; ++j) {
            unsigned short hb = f2bf_rne(va[j]);
            h0[j] = (short)hb; l0[j] = (short)f2bf_rne(va[j] - bfu2f(hb));
            unsigned short hb2 = f2bf_rne(va[8 + j]);
            h1[j] = (short)hb2; l1[j] = (short)f2bf_rne(va[8 + j] - bfu2f(hb2));
        }
        int base = sm * 40 + sk;
        *(bh8*)&As_hi[buf][base] = h0; *(bh8*)&As_hi[buf][base + 8] = h1;
        *(bh8*)&As_lo[buf][base] = l0; *(bh8*)&As_lo[buf][base + 8] = l1;
    };

    {   // prologue: stage iter 0
        float va[16];
        load_src(0, va);
        write_lds(0, va);
    }
    __syncthreads();

    for (int it = 0; it < 13; ++it) {
        const int buf = it & 1;
        // issue next iter's global loads early (latency hides under MFMA)
        float vnext[16];
        if (it + 1 < 13) load_src(it + 1, vnext);

        // B fragments for this iter
        bh8 bhf[4], blf[4];
        if (it < 5) {
            int k0 = it * 32;
#pragma unroll
            for (int nt = 0; nt < 4; ++nt) {
                int n = colb + wn + nt * 16 + fm;
                size_t off = (size_t)n * 160 + k0 + fk;
                bhf[nt] = *(const bh8*)(WibT_hi + off);
                blf[nt] = *(const bh8*)(WibT_lo + off);
            }
        } else {
            int k0 = (it - 5) * 32;
#pragma unroll
            for (int nt = 0; nt < 4; ++nt) {
                int n = colb + wn + nt * 16 + fm;
                size_t off = (size_t)n * 256 + k0 + fk;
                bhf[nt] = *(const bh8*)(WhT_hi + off);
                blf[nt] = *(const bh8*)(WhT_lo + off);
            }
        }
#pragma unroll
        for (int mt = 0; mt < 4; ++mt) {
            int abase = (wm + mt * 16 + fm) * 40 + fk;
            bh8 ah = *(const bh8*)&As_hi[buf][abase];
            bh8 al = *(const bh8*)&As_lo[buf][abase];
#pragma unroll
            for (int nt = 0; nt < 4; ++nt) {
                acc[mt][nt] = mfma16(ah, bhf[nt], acc[mt][nt]);
                acc[mt][nt] = mfma16(ah, blf[nt], acc[mt][nt]);
                acc[mt][nt] = mfma16(al, bhf[nt], acc[mt][nt]);
            }
        }

        if (it == 4) {   // phase boundary: input_bond relu (per-wave registers)
#pragma unroll
            for (int i = 0; i < 4; ++i)
#pragma unroll
                for (int j = 0; j < 4; ++j)
#pragma unroll
                    for (int r = 0; r < 4; ++r)
                        acc[i][j][r] = fmaxf(acc[i][j][r], 0.f);
        }

        if (it + 1 < 13) write_lds(buf ^ 1, vnext);
        __syncthreads();
    }

    // epilogue: relu * MB_SCALE -> fp16 (C layout: col=lane&15, row=(lane>>4)*4+r)
#pragma unroll
    for (int mt = 0; mt < 4; ++mt) {
        int rbase = row0 + wm + mt * 16 + (lane >> 4) * 4;
#pragma unroll
        for (int nt = 0; nt < 4; ++nt) {
            int col = colb + wn + nt * 16 + fm;
#pragma unroll
            for (int r = 0; r < 4; ++r) {
                int row = rbase + r;
                if (row < M)
                    mb_new[(size_t)row * 256 + col] =
                        (f16)(fmaxf(acc[mt][nt][r], 0.f) * MB_SCALE);
            }
        }
    }
}

// ---------------------------------------------------------------------------
// agg = sum_j(mb[a2b[a,j]]) * max_j(mb[a2b[a,j]]), vectorized:
// 4 atoms/block, 64 lanes/atom, f16x4 loads (full 512B row per neighbor).
// ---------------------------------------------------------------------------
__global__ __launch_bounds__(256) void agg_kernel(
    const f16* __restrict__ mb, const int* __restrict__ a2b,
    float* __restrict__ matom, float* __restrict__ agg_out, int A)
{
    const int g    = threadIdx.x >> 6;
    const int lane = threadIdx.x & 63;
    const int a = blockIdx.x * 4 + g;
    if (a >= A) return;
    const int* nb = a2b + (size_t)a * 6;
    int i0 = nb[0], i1 = nb[1], i2 = nb[2], i3 = nb[3], i4 = nb[4], i5 = nb[5];
    const size_t co = (size_t)lane * 4;
    f16x4 v0 = *(const f16x4*)(mb + (size_t)i0 * 256 + co);
    f16x4 v1 = *(const f16x4*)(mb + (size_t)i1 * 256 + co);
    f16x4 v2 = *(const f16x4*)(mb + (size_t)i2 * 256 + co);
    f16x4 v3 = *(const f16x4*)(mb + (size_t)i3 * 256 + co);
    f16x4 v4 = *(const f16x4*)(mb + (size_t)i4 * 256 + co);
    f16x4 v5 = *(const f16x4*)(mb + (size_t)i5 * 256 + co);
    float gva[4];
#pragma unroll
    for (int c = 0; c < 4; ++c) {
        float f0 = (float)v0[c], f1 = (float)v1[c], f2 = (float)v2[c];
        float f3 = (float)v3[c], f4 = (float)v4[c], f5 = (float)v5[c];
        float s  = f0 + f1 + f2 + f3 + f4 + f5;
        float mx = fmaxf(fmaxf(fmaxf(f0, f1), fmaxf(f2, f3)), fmaxf(f4, f5));
        gva[c] = AGG_INV * s * mx;
    }
    size_t o = (size_t)a * 256 + co;
    if (agg_out) {
        *(float4*)(agg_out + o) = make_float4(gva[0], gva[1], gva[2], gva[3]);
    } else {
        float4 m = *(const float4*)(matom + o);
        m.x += gva[0]; m.y += gva[1]; m.z += gva[2]; m.w += gva[3];
        *(float4*)(matom + o) = m;
    }
}

// Exclusive prefix sum of sizes -> offsets (one block, M=5000). Raw, unclipped.
__global__ __launch_bounds__(256) void scan_kernel(
    const int* __restrict__ sizes, int* __restrict__ offsets, int M)
{
    __shared__ int part[256];
    const int t = threadIdx.x;
    const int chunk = (M + 255) / 256;
    int begin = t * chunk;
    int end = begin + chunk; if (end > M) end = M;
    int s = 0;
    for (int i = begin; i < end && i < M; ++i) s += sizes[i];
    part[t] = s;
    __syncthreads();
    for (int off = 1; off < 256; off <<= 1) {
        int v = (t >= off) ? part[t - off] : 0;
        __syncthreads();
        part[t] += v;
        __syncthreads();
    }
    int run = part[t] - s;
    for (int i = begin; i < end && i < M; ++i) { offsets[i] = run; run += sizes[i]; }
}

// Per-molecule mean pooling with jnp.repeat(total_repeat_length=A) DROP
// semantics (sizes[M-1] may be negative).
__global__ __launch_bounds__(256) void pool_kernel(
    const float* __restrict__ hid, const int* __restrict__ offsets,
    const int* __restrict__ sizes, float* __restrict__ out, int M, int A)
{
    const int m = blockIdx.x;
    const int h = threadIdx.x;
    int e = offsets[m];
    int sz = sizes[m];
    int start = e < A ? e : A;          if (start < 0) start = 0;
    int stop  = e + sz; if (stop > A) stop = A; if (stop < 0) stop = 0;
    float s = 0.f;
    for (int i = start; i < stop; ++i)
        s += hid[(size_t)i * 256 + h];
    out[(size_t)m * 256 + h] = s / (float)sz;
}

extern "C" void kernel_launch(void* const* d_in, const int* in_sizes, int n_in,
                              void* d_out, int out_size, void* d_ws, size_t ws_size,
                              hipStream_t stream)
{
    const float* f_atoms = (const float*)d_in[0];
    const float* f_bonds = (const float*)d_in[1];
    const float* W_ia    = (const float*)d_in[2];
    const float* W_ib    = (const float*)d_in[3];
    const float* W_h     = (const float*)d_in[4];
    const float* W_o     = (const float*)d_in[5];
    const float* b_o     = (const float*)d_in[6];
    const float* W_lr    = (const float*)d_in[7];
    const int*   a2b     = (const int*)d_in[8];
    const int*   b2a     = (const int*)d_in[9];
    const int*   b2revb  = (const int*)d_in[10];
    const int*   sizes   = (const int*)d_in[11];
    float* out = (float*)d_out;   // fp32 [5000,256]

    const int An = 100000, Bn = 200000, Mm = 5000;
    const size_t ABYTES = (size_t)An * 256 * 4;
    const size_t BBYTES = (size_t)Bn * 256 * 2;

    int*   offsets = (int*)d_ws;
    float* matom   = (float*)((char*)d_ws + 32768);
    f16*   mb0     = (f16*)((char*)matom + ABYTES);
    f16*   mb1     = (f16*)((char*)mb0 + BBYTES);
    short* wsplit  = (short*)((char*)mb1 + BBYTES);
    // total footprint unchanged: 358,432,768 B (proven safe)

    short* WiaT_hi = wsplit;
    short* WiaT_lo = wsplit + 40960;
    short* WibT_hi = wsplit + 81920;
    short* WibT_lo = wsplit + 122880;
    short* WhT_hi  = wsplit + 163840;
    short* WhT_lo  = wsplit + 360448;
    short* WlrT_hi = wsplit + 557056;
    short* WlrT_lo = wsplit + 753664;
    short* WoT_hi  = wsplit + 950272;
    short* WoT_lo  = wsplit + 1015808;

    dim3 blk(256);
    dim3 gA((An + 127) / 128, 2);
    dim3 gB((Bn + 127) / 128, 2);

    wprep_kernel<<<2112, blk, 0, stream>>>(W_ia, W_ib, W_h, W_lr, W_o, wsplit);

    mfma_gemm<160, 0, 0><<<gA, blk, 0, stream>>>(
        f_atoms, nullptr, nullptr, WiaT_hi, WiaT_lo, nullptr, matom, An, 133);
    mfma_gemm<160, 0, 2><<<gB, blk, 0, stream>>>(
        f_bonds, nullptr, nullptr, WibT_hi, WibT_lo, nullptr, mb0, Bn, 147);

    f16* cur = mb0; f16* nxt = mb1;
    for (int d = 0; d < 3; ++d) {
        agg_kernel<<<(An + 3) / 4, blk, 0, stream>>>(cur, a2b, matom, (float*)nullptr, An);
        bond_mfma_kernel<<<gB, blk, 0, stream>>>(
            f_bonds, WibT_hi, WibT_lo,
            WhT_hi + (size_t)d * 65536, WhT_lo + (size_t)d * 65536,
            matom, cur, b2a, b2revb, nxt, Bn);
        f16* t = cur; cur = nxt; nxt = t;
    }
    // cur = mb1 (final message_bond), nxt = mb0 (free)

    float* aggbuf = (float*)mb0;
    agg_kernel<<<(An + 3) / 4, blk, 0, stream>>>(cur, a2b, matom, aggbuf, An);

    unsigned short* iatom = (unsigned short*)mb1;
    unsigned short* t1    = (unsigned short*)((char*)mb1 + 51200000);
    mfma_gemm<160, 0, 1><<<gA, blk, 0, stream>>>(
        f_atoms, nullptr, nullptr, WiaT_hi, WiaT_lo, nullptr, iatom, An, 133);

    mfma_gemm<768, 1, 3><<<gA, blk, 0, stream>>>(
        aggbuf, matom, iatom, WlrT_hi, WlrT_lo, nullptr, t1, An, 768);

    float* hid = (float*)mb0;
    mfma_gemm<256, 2, 4><<<gA, blk, 0, stream>>>(
        t1, nullptr, nullptr, WoT_hi, WoT_lo, b_o, hid, An, 256);

    scan_kernel<<<1, 256, 0, stream>>>(sizes, offsets, Mm);
    pool_kernel<<<Mm, blk, 0, stream>>>(hid, offsets, sizes, out, Mm, An);
}